// Round 3
// baseline (278.834 us; speedup 1.0000x reference)
//
#include <hip/hip_runtime.h>

// ResNeXt sparse-voxel block, MI355X. Round 2: MFMA pair-list sparse conv.
// H stored bf16; W pre-transposed to bf16 [col][kin]; per-k-offset the conv is
// gather[E,32] x W[32,32] done as mfma_f32_16x16x32_bf16 with A gathered
// straight into fragments (global->reg, shfl-broadcast indices) and C/D
// scatter-added into an LDS tile (unique outputs within k => race-free;
// per-k barrier => deterministic cross-k order; tail entries -> dump row).

#define NN    65536
#define CIN   128
#define CPATH 32
#define NPATH 4
#define NK    27
#define TJ    256
#define NTILE (NN / TJ)    // 256

typedef __attribute__((ext_vector_type(8))) short bfx8;
typedef __attribute__((ext_vector_type(4))) float fx4;

__device__ __forceinline__ unsigned short f2bf(float f) {
    unsigned u = __builtin_bit_cast(unsigned, f);
    u += 0x7FFFu + ((u >> 16) & 1u);
    return (unsigned short)(u >> 16);
}

// ---------------------------------------------------------------------------
// Kernel 1: H = feats @ Wcat + bcat, stored as bf16 [NN][128].
// f32 SIMT compute (128x128 tile, 8x8/thread), bf16 convert in epilogue.
// ---------------------------------------------------------------------------
__global__ void lin_gemm(const float* __restrict__ feats,
                         const float* __restrict__ linW,
                         const float* __restrict__ linb,
                         unsigned short* __restrict__ Hb) {
    __shared__ float As[32][132];
    __shared__ float Bs[32][132];
    const int tid = threadIdx.x;
    const int row0 = blockIdx.x * 128;
    const int rg = tid >> 4, cg = tid & 15;

    float acc[8][8];
#pragma unroll
    for (int i = 0; i < 8; i++)
#pragma unroll
        for (int j = 0; j < 8; j++) acc[i][j] = 0.f;

    for (int kt = 0; kt < 4; ++kt) {
        {
            const int r = tid >> 3;
            const int kq = tid & 7;
#pragma unroll
            for (int i = 0; i < 4; i++) {
                const float4 v = *(const float4*)(feats +
                    (size_t)(row0 + r + 32 * i) * CIN + kt * 32 + kq * 4);
                As[kq * 4 + 0][r + 32 * i] = v.x;
                As[kq * 4 + 1][r + 32 * i] = v.y;
                As[kq * 4 + 2][r + 32 * i] = v.z;
                As[kq * 4 + 3][r + 32 * i] = v.w;
            }
        }
        {
            const int col4 = (tid & 31) * 4;
            const int kk0 = tid >> 5;
            const int p = col4 >> 5;
#pragma unroll
            for (int i = 0; i < 4; i++) {
                const int kk = kk0 + 8 * i;
                const float4 w = *(const float4*)(linW +
                    ((size_t)(p * CIN) + (kt * 32 + kk)) * CPATH + (col4 & 31));
                *(float4*)&Bs[kk][col4] = w;
            }
        }
        __syncthreads();
#pragma unroll
        for (int kk = 0; kk < 32; kk++) {
            float a[8], b[8];
            *(float4*)&a[0] = *(const float4*)&As[kk][rg * 8];
            *(float4*)&a[4] = *(const float4*)&As[kk][rg * 8 + 4];
            *(float4*)&b[0] = *(const float4*)&Bs[kk][cg * 8];
            *(float4*)&b[4] = *(const float4*)&Bs[kk][cg * 8 + 4];
#pragma unroll
            for (int i = 0; i < 8; i++)
#pragma unroll
                for (int j = 0; j < 8; j++)
                    acc[i][j] = fmaf(a[i], b[j], acc[i][j]);
        }
        __syncthreads();
    }
    float bias[8];
#pragma unroll
    for (int j = 0; j < 8; j++) bias[j] = linb[cg * 8 + j];
#pragma unroll
    for (int i = 0; i < 8; i++) {
        const int row = row0 + rg * 8 + i;
        union { unsigned short s[8]; uint4 v; } u;
#pragma unroll
        for (int j = 0; j < 8; j++) u.s[j] = f2bf(acc[i][j] + bias[j]);
        *(uint4*)(Hb + (size_t)row * CIN + cg * 8) = u.v;
    }
}

// ---------------------------------------------------------------------------
// W prep: Wt[p][k][col][kin] = bf16(convW[p][k][kin][col])  (B^T for MFMA)
// ---------------------------------------------------------------------------
__global__ void wprep(const float* __restrict__ convW,
                      unsigned short* __restrict__ Wt) {
    const int pk = blockIdx.x;            // 0..107
    const int t = threadIdx.x;            // 256
    const int m = t >> 3;
    const int c0 = (t & 7) * 4;
    const float4 w = *(const float4*)(convW + ((size_t)pk * CPATH + m) * CPATH + c0);
    unsigned short* o = Wt + (size_t)pk * CPATH * CPATH;
    o[(c0 + 0) * CPATH + m] = f2bf(w.x);
    o[(c0 + 1) * CPATH + m] = f2bf(w.y);
    o[(c0 + 2) * CPATH + m] = f2bf(w.z);
    o[(c0 + 3) * CPATH + m] = f2bf(w.w);
}

// ---------------------------------------------------------------------------
// sconv3: MFMA sparse conv per (path, 256-voxel tile).
// ---------------------------------------------------------------------------
__global__ void __launch_bounds__(256, 4)
sconv3(const unsigned short* __restrict__ Hb,
       const unsigned short* __restrict__ Wt,
       const int* __restrict__ im,
       const int* __restrict__ om,
       float* __restrict__ Cb,
       float* __restrict__ part) {
    __shared__ __align__(16) float Ct[TJ + 1][36];  // +1 dump row, +4 pad
    __shared__ int rng[NK][2];
    __shared__ float red[8][64];

    const int p = blockIdx.y;
    const int j0 = blockIdx.x * TJ;
    const int tid = threadIdx.x;
    const int w = tid >> 6;
    const int lane = tid & 63;

    {   // zero tile (incl. dump row)
        float* ctf = &Ct[0][0];
        const float4 z = make_float4(0.f, 0.f, 0.f, 0.f);
        for (int idx = tid * 4; idx < (TJ + 1) * 36; idx += 1024)
            *(float4*)&ctf[idx] = z;
    }
    if (tid < NK * 2) {   // 54 binary searches on sorted out_map lists
        const int k = tid >> 1;
        const int bound = (tid & 1) ? (j0 + TJ) : j0;
        const int* o = om + ((size_t)p * NK + k) * NN;
        int lo = 0, hi = NN;
        while (lo < hi) {
            const int mid = (lo + hi) >> 1;
            if (o[mid] < bound) lo = mid + 1; else hi = mid;
        }
        rng[k][tid & 1] = lo;
    }
    __syncthreads();

    const int mrow = lane & 15;   // A row / C col
    const int kq = lane >> 4;     // k-slice (A/B), row-group (C/D)

    for (int k = 0; k < NK; ++k) {
        const int s = rng[k][0];
        const int e = rng[k][1];
        const int* ok = om + ((size_t)p * NK + k) * NN;
        const int* ik = im + ((size_t)p * NK + k) * NN;
        const unsigned short* Wk = Wt + ((size_t)p * NK + k) * CPATH * CPATH;
        const bfx8 b0 = *(const bfx8*)(Wk + (size_t)mrow * CPATH + kq * 8);
        const bfx8 b1 = *(const bfx8*)(Wk + (size_t)(16 + mrow) * CPATH + kq * 8);
        const int nchunk = (e - s + 31) >> 5;
        for (int c = (w - k) & 3; c < nchunk; c += 4) {
            const int t = s + (c << 5) + (lane & 31);
            int jjv = TJ, iiv = 0;
            if (t < e) { jjv = ok[t] - j0; iiv = ik[t]; }
            const int iA0 = __shfl(iiv, mrow, 64);
            const int iA1 = __shfl(iiv, 16 + mrow, 64);
            const bfx8 a0 = *(const bfx8*)(Hb + (size_t)iA0 * CIN + p * CPATH + kq * 8);
            const bfx8 a1 = *(const bfx8*)(Hb + (size_t)iA1 * CIN + p * CPATH + kq * 8);
            const fx4 z = {0.f, 0.f, 0.f, 0.f};
            const fx4 c00 = __builtin_amdgcn_mfma_f32_16x16x32_bf16(a0, b0, z, 0, 0, 0);
            const fx4 c01 = __builtin_amdgcn_mfma_f32_16x16x32_bf16(a0, b1, z, 0, 0, 0);
            const fx4 c10 = __builtin_amdgcn_mfma_f32_16x16x32_bf16(a1, b0, z, 0, 0, 0);
            const fx4 c11 = __builtin_amdgcn_mfma_f32_16x16x32_bf16(a1, b1, z, 0, 0, 0);
#pragma unroll
            for (int r = 0; r < 4; ++r) {
                const int jr0 = __shfl(jjv, kq * 4 + r, 64);
                const int jr1 = __shfl(jjv, 16 + kq * 4 + r, 64);
                atomicAdd(&Ct[jr0][mrow], c00[r]);
                atomicAdd(&Ct[jr0][16 + mrow], c01[r]);
                atomicAdd(&Ct[jr1][mrow], c10[r]);
                atomicAdd(&Ct[jr1][16 + mrow], c11[r]);
            }
        }
        __syncthreads();   // serialize k's -> deterministic cross-k accumulation
    }

    // fused BN partial sums (rows 0..255 only)
    {
        const int c = tid & 31;
        const int h = tid >> 5;
        float s = 0.f, s2 = 0.f;
#pragma unroll
        for (int r = 0; r < 32; r++) {
            const float v = Ct[h * 32 + r][c];
            s += v;
            s2 = fmaf(v, v, s2);
        }
        red[h][c] = s;
        red[h][32 + c] = s2;
    }
    __syncthreads();
    if (tid < 64) {
        float s = red[0][tid];
#pragma unroll
        for (int h = 1; h < 8; h++) s += red[h][tid];
        part[(((size_t)p * NTILE) + blockIdx.x) * 64 + tid] = s;
    }

    // writeback
    {
        const int cq8 = tid & 7;
        const int r0 = tid >> 3;
#pragma unroll
        for (int m = 0; m < 8; m++) {
            const int r = r0 + 32 * m;
            *(float4*)(Cb + (size_t)(j0 + r) * CIN + p * CPATH + cq8 * 4) =
                *(const float4*)&Ct[r][cq8 * 4];
        }
    }
}

// ---------------------------------------------------------------------------
// BN finalize: reduce per-tile partials -> scale/shift per channel.
// ---------------------------------------------------------------------------
__global__ void bn_stats2(const float* __restrict__ part,
                          const float* __restrict__ gamma,
                          const float* __restrict__ beta,
                          float* __restrict__ ss) {
    const int c = threadIdx.x;  // 0..127
    const int p = c >> 5, cc = c & 31;
    float s = 0.f, s2 = 0.f;
    for (int t = 0; t < NTILE; t++) {
        s += part[(((size_t)p * NTILE) + t) * 64 + cc];
        s2 += part[(((size_t)p * NTILE) + t) * 64 + 32 + cc];
    }
    const float mean = s * (1.f / NN);
    const float var = s2 * (1.f / NN) - mean * mean;
    const float sc = gamma[c] * rsqrtf(var + 1e-5f);
    ss[c] = sc;
    ss[128 + c] = beta[c] - mean * sc;
}

// ---------------------------------------------------------------------------
// Final GEMM: out = relu(norm(Cb)) @ finW + finb + feats
// ---------------------------------------------------------------------------
__global__ void fin_gemm(const float* __restrict__ Cb,
                         const float* __restrict__ scale,
                         const float* __restrict__ shift,
                         const float* __restrict__ finW,
                         const float* __restrict__ finb,
                         const float* __restrict__ feats,
                         float* __restrict__ out) {
    __shared__ float As[32][132];
    __shared__ float Bs[32][132];
    const int tid = threadIdx.x;
    const int row0 = blockIdx.x * 128;
    const int rg = tid >> 4, cg = tid & 15;

    float acc[8][8];
#pragma unroll
    for (int i = 0; i < 8; i++)
#pragma unroll
        for (int j = 0; j < 8; j++) acc[i][j] = 0.f;

    for (int kt = 0; kt < 4; ++kt) {
        {
            const int r = tid >> 3;
            const int kq = tid & 7;
            const int kbase = kt * 32 + kq * 4;
            const float sc0 = scale[kbase + 0], sh0 = shift[kbase + 0];
            const float sc1 = scale[kbase + 1], sh1 = shift[kbase + 1];
            const float sc2 = scale[kbase + 2], sh2 = shift[kbase + 2];
            const float sc3 = scale[kbase + 3], sh3 = shift[kbase + 3];
#pragma unroll
            for (int i = 0; i < 4; i++) {
                const float4 v = *(const float4*)(Cb +
                    (size_t)(row0 + r + 32 * i) * CIN + kbase);
                As[kq * 4 + 0][r + 32 * i] = fmaxf(fmaf(v.x, sc0, sh0), 0.f);
                As[kq * 4 + 1][r + 32 * i] = fmaxf(fmaf(v.y, sc1, sh1), 0.f);
                As[kq * 4 + 2][r + 32 * i] = fmaxf(fmaf(v.z, sc2, sh2), 0.f);
                As[kq * 4 + 3][r + 32 * i] = fmaxf(fmaf(v.w, sc3, sh3), 0.f);
            }
        }
        {
            const int col4 = (tid & 31) * 4;
            const int kk0 = tid >> 5;
#pragma unroll
            for (int i = 0; i < 4; i++) {
                const int kk = kk0 + 8 * i;
                const float4 w = *(const float4*)(finW +
                    (size_t)(kt * 32 + kk) * CIN + col4);
                *(float4*)&Bs[kk][col4] = w;
            }
        }
        __syncthreads();
#pragma unroll
        for (int kk = 0; kk < 32; kk++) {
            float a[8], b[8];
            *(float4*)&a[0] = *(const float4*)&As[kk][rg * 8];
            *(float4*)&a[4] = *(const float4*)&As[kk][rg * 8 + 4];
            *(float4*)&b[0] = *(const float4*)&Bs[kk][cg * 8];
            *(float4*)&b[4] = *(const float4*)&Bs[kk][cg * 8 + 4];
#pragma unroll
            for (int i = 0; i < 8; i++)
#pragma unroll
                for (int j = 0; j < 8; j++)
                    acc[i][j] = fmaf(a[i], b[j], acc[i][j]);
        }
        __syncthreads();
    }
    float fb[8];
#pragma unroll
    for (int j = 0; j < 8; j++) fb[j] = finb[cg * 8 + j];
#pragma unroll
    for (int i = 0; i < 8; i++) {
        const int row = row0 + rg * 8 + i;
        const float4 r0 = *(const float4*)(feats + (size_t)row * CIN + cg * 8);
        const float4 r1 = *(const float4*)(feats + (size_t)row * CIN + cg * 8 + 4);
        float4 o0, o1;
        o0.x = acc[i][0] + fb[0] + r0.x; o0.y = acc[i][1] + fb[1] + r0.y;
        o0.z = acc[i][2] + fb[2] + r0.z; o0.w = acc[i][3] + fb[3] + r0.w;
        o1.x = acc[i][4] + fb[4] + r1.x; o1.y = acc[i][5] + fb[5] + r1.y;
        o1.z = acc[i][6] + fb[6] + r1.z; o1.w = acc[i][7] + fb[7] + r1.w;
        *(float4*)(out + (size_t)row * CIN + cg * 8) = o0;
        *(float4*)(out + (size_t)row * CIN + cg * 8 + 4) = o1;
    }
}

// ---------------------------------------------------------------------------
extern "C" void kernel_launch(void* const* d_in, const int* in_sizes, int n_in,
                              void* d_out, int out_size, void* d_ws,
                              size_t ws_size, hipStream_t stream) {
    (void)in_sizes; (void)n_in; (void)out_size; (void)ws_size;
    const float* feats = (const float*)d_in[0];
    const float* linW  = (const float*)d_in[1];
    const float* linb  = (const float*)d_in[2];
    const float* convW = (const float*)d_in[3];
    const float* gamma = (const float*)d_in[4];
    const float* beta  = (const float*)d_in[5];
    const float* finW  = (const float*)d_in[6];
    const float* finb  = (const float*)d_in[7];
    const int*   im    = (const int*)d_in[8];
    const int*   om    = (const int*)d_in[9];
    float* out = (float*)d_out;

    char* ws = (char*)d_ws;
    unsigned short* Hb = (unsigned short*)(ws);            // 16,777,216 B
    float* Cb          = (float*)(ws + 16777216);          // 33,554,432 B
    unsigned short* Wt = (unsigned short*)(ws + 50331648); //    221,184 B
    float* part        = (float*)(ws + 50552832);          //    262,144 B
    float* ss          = (float*)(ws + 50814976);          //      1,024 B

    wprep<<<NPATH * NK, 256, 0, stream>>>(convW, Wt);
    lin_gemm<<<512, 256, 0, stream>>>(feats, linW, linb, Hb);
    sconv3<<<dim3(NTILE, NPATH), 256, 0, stream>>>(Hb, Wt, im, om, Cb, part);
    bn_stats2<<<1, 128, 0, stream>>>(part, gamma, beta, ss);
    fin_gemm<<<512, 256, 0, stream>>>(Cb, ss, ss + 128, finW, finb, feats, out);
}

// Round 4
// 126.805 us; speedup vs baseline: 2.1989x; 2.1989x over previous
//
#include <hip/hip_runtime.h>

// ResNeXt sparse-voxel block, MI355X. Round 3: gather-register MFMA conv.
// sconv4: per (path, 256-row tile) stage idxT[row][k] (input row or sentinel)
// from the sorted pair lists, then accumulate over all 27 k in MFMA C regs:
// acc = mfma(A_gather(idxT[row][k]), W_k, acc). No atomics, no per-k barrier,
// deterministic. Sentinel gathers hit zeroed row NN of Hb (L1 broadcast).

#define NN    65536
#define CIN   128
#define CPATH 32
#define NPATH 4
#define NK    27
#define TJ    256
#define NTILE (NN / TJ)    // 256

typedef __attribute__((ext_vector_type(8))) short bfx8;
typedef __attribute__((ext_vector_type(4))) float fx4;

__device__ __forceinline__ unsigned short f2bf(float f) {
    unsigned u = __builtin_bit_cast(unsigned, f);
    u += 0x7FFFu + ((u >> 16) & 1u);
    return (unsigned short)(u >> 16);
}

// ---------------------------------------------------------------------------
// Kernel 1: H = feats @ Wcat + bcat, stored as bf16 [NN+1][128] (row NN = 0).
// ---------------------------------------------------------------------------
__global__ void lin_gemm(const float* __restrict__ feats,
                         const float* __restrict__ linW,
                         const float* __restrict__ linb,
                         unsigned short* __restrict__ Hb) {
    __shared__ float As[32][132];
    __shared__ float Bs[32][132];
    const int tid = threadIdx.x;
    const int row0 = blockIdx.x * 128;
    const int rg = tid >> 4, cg = tid & 15;

    float acc[8][8];
#pragma unroll
    for (int i = 0; i < 8; i++)
#pragma unroll
        for (int j = 0; j < 8; j++) acc[i][j] = 0.f;

    for (int kt = 0; kt < 4; ++kt) {
        {
            const int r = tid >> 3;
            const int kq = tid & 7;
#pragma unroll
            for (int i = 0; i < 4; i++) {
                const float4 v = *(const float4*)(feats +
                    (size_t)(row0 + r + 32 * i) * CIN + kt * 32 + kq * 4);
                As[kq * 4 + 0][r + 32 * i] = v.x;
                As[kq * 4 + 1][r + 32 * i] = v.y;
                As[kq * 4 + 2][r + 32 * i] = v.z;
                As[kq * 4 + 3][r + 32 * i] = v.w;
            }
        }
        {
            const int col4 = (tid & 31) * 4;
            const int kk0 = tid >> 5;
            const int p = col4 >> 5;
#pragma unroll
            for (int i = 0; i < 4; i++) {
                const int kk = kk0 + 8 * i;
                const float4 w = *(const float4*)(linW +
                    ((size_t)(p * CIN) + (kt * 32 + kk)) * CPATH + (col4 & 31));
                *(float4*)&Bs[kk][col4] = w;
            }
        }
        __syncthreads();
#pragma unroll
        for (int kk = 0; kk < 32; kk++) {
            float a[8], b[8];
            *(float4*)&a[0] = *(const float4*)&As[kk][rg * 8];
            *(float4*)&a[4] = *(const float4*)&As[kk][rg * 8 + 4];
            *(float4*)&b[0] = *(const float4*)&Bs[kk][cg * 8];
            *(float4*)&b[4] = *(const float4*)&Bs[kk][cg * 8 + 4];
#pragma unroll
            for (int i = 0; i < 8; i++)
#pragma unroll
                for (int j = 0; j < 8; j++)
                    acc[i][j] = fmaf(a[i], b[j], acc[i][j]);
        }
        __syncthreads();
    }
    float bias[8];
#pragma unroll
    for (int j = 0; j < 8; j++) bias[j] = linb[cg * 8 + j];
#pragma unroll
    for (int i = 0; i < 8; i++) {
        const int row = row0 + rg * 8 + i;
        union { unsigned short s[8]; uint4 v; } u;
#pragma unroll
        for (int j = 0; j < 8; j++) u.s[j] = f2bf(acc[i][j] + bias[j]);
        *(uint4*)(Hb + (size_t)row * CIN + cg * 8) = u.v;
    }
}

// ---------------------------------------------------------------------------
// W prep: Wt[p][k][col][kin] = bf16(convW[p][k][kin][col]); block 0 also
// zeros Hb row NN (the sentinel row).
// ---------------------------------------------------------------------------
__global__ void wprep(const float* __restrict__ convW,
                      unsigned short* __restrict__ Wt,
                      unsigned short* __restrict__ Hb) {
    const int pk = blockIdx.x;            // 0..107
    const int t = threadIdx.x;            // 256
    if (pk == 0 && t < 64)
        ((unsigned*)(Hb + (size_t)NN * CIN))[t] = 0u;
    const int m = t >> 3;
    const int c0 = (t & 7) * 4;
    const float4 w = *(const float4*)(convW + ((size_t)pk * CPATH + m) * CPATH + c0);
    unsigned short* o = Wt + (size_t)pk * CPATH * CPATH;
    o[(c0 + 0) * CPATH + m] = f2bf(w.x);
    o[(c0 + 1) * CPATH + m] = f2bf(w.y);
    o[(c0 + 2) * CPATH + m] = f2bf(w.z);
    o[(c0 + 3) * CPATH + m] = f2bf(w.w);
}

// ---------------------------------------------------------------------------
// sconv4: gather-register MFMA conv per (path, 256-row tile).
// 4 waves x 64 rows each (4 fragments); acc over k in registers.
// ---------------------------------------------------------------------------
__global__ void __launch_bounds__(256, 4)
sconv4(const unsigned short* __restrict__ Hb,
       const unsigned short* __restrict__ Wt,
       const int* __restrict__ im,
       const int* __restrict__ om,
       float* __restrict__ Cb,
       float* __restrict__ part) {
    __shared__ int idxT[TJ][29];      // [row][k], 29 = odd pad (conflict-free)
    __shared__ int rng[NK][2];
    __shared__ float red[4][64];

    const int p = blockIdx.y;
    const int j0 = blockIdx.x * TJ;
    const int tid = threadIdx.x;
    const int w = tid >> 6, lane = tid & 63;
    const int mrow = lane & 15, kq = lane >> 4;

    // sentinel-init idxT (covers pad; harmless)
    for (int idx = tid; idx < TJ * 29; idx += 256)
        (&idxT[0][0])[idx] = NN;
    // 54 binary searches on the sorted out_map lists
    if (tid < NK * 2) {
        const int k = tid >> 1;
        const int bound = (tid & 1) ? (j0 + TJ) : j0;
        const int* o = om + ((size_t)p * NK + k) * NN;
        int lo = 0, hi = NN;
        while (lo < hi) {
            const int mid = (lo + hi) >> 1;
            if (o[mid] < bound) lo = mid + 1; else hi = mid;
        }
        rng[k][tid & 1] = lo;
    }
    __syncthreads();
    // scatter-fill idxT from pair lists (8 threads per k; rows unique per k)
    {
        const int k = tid >> 3;
        if (k < NK) {
            const int s = rng[k][0], e = rng[k][1];
            const int* ok = om + ((size_t)p * NK + k) * NN;
            const int* ik = im + ((size_t)p * NK + k) * NN;
            for (int t = s + (tid & 7); t < e; t += 8)
                idxT[ok[t] - j0][k] = ik[t];
        }
    }
    __syncthreads();

    // k-accumulation loop, all in registers
    fx4 acc[4][2];
#pragma unroll
    for (int f = 0; f < 4; f++)
#pragma unroll
        for (int h = 0; h < 2; h++) acc[f][h] = (fx4){0.f, 0.f, 0.f, 0.f};

    const unsigned short* Wp = Wt + (size_t)p * NK * CPATH * CPATH;
    const unsigned short* Hp = Hb + (size_t)p * CPATH + kq * 8;
    const int rbase = w * 64 + mrow;

#pragma unroll 3
    for (int k = 0; k < NK; ++k) {
        const bfx8 b0 = *(const bfx8*)(Wp + (size_t)k * 1024 + mrow * CPATH + kq * 8);
        const bfx8 b1 = *(const bfx8*)(Wp + (size_t)k * 1024 + (16 + mrow) * CPATH + kq * 8);
        const int i0 = idxT[rbase +  0][k];
        const int i1 = idxT[rbase + 16][k];
        const int i2 = idxT[rbase + 32][k];
        const int i3 = idxT[rbase + 48][k];
        const bfx8 a0 = *(const bfx8*)(Hp + (size_t)i0 * CIN);
        const bfx8 a1 = *(const bfx8*)(Hp + (size_t)i1 * CIN);
        const bfx8 a2 = *(const bfx8*)(Hp + (size_t)i2 * CIN);
        const bfx8 a3 = *(const bfx8*)(Hp + (size_t)i3 * CIN);
        acc[0][0] = __builtin_amdgcn_mfma_f32_16x16x32_bf16(a0, b0, acc[0][0], 0, 0, 0);
        acc[0][1] = __builtin_amdgcn_mfma_f32_16x16x32_bf16(a0, b1, acc[0][1], 0, 0, 0);
        acc[1][0] = __builtin_amdgcn_mfma_f32_16x16x32_bf16(a1, b0, acc[1][0], 0, 0, 0);
        acc[1][1] = __builtin_amdgcn_mfma_f32_16x16x32_bf16(a1, b1, acc[1][1], 0, 0, 0);
        acc[2][0] = __builtin_amdgcn_mfma_f32_16x16x32_bf16(a2, b0, acc[2][0], 0, 0, 0);
        acc[2][1] = __builtin_amdgcn_mfma_f32_16x16x32_bf16(a2, b1, acc[2][1], 0, 0, 0);
        acc[3][0] = __builtin_amdgcn_mfma_f32_16x16x32_bf16(a3, b0, acc[3][0], 0, 0, 0);
        acc[3][1] = __builtin_amdgcn_mfma_f32_16x16x32_bf16(a3, b1, acc[3][1], 0, 0, 0);
    }

    // BN partials straight from acc regs: lane holds cols (mrow, 16+mrow)
    {
        float s0 = 0.f, q0 = 0.f, s1 = 0.f, q1 = 0.f;
#pragma unroll
        for (int f = 0; f < 4; f++)
#pragma unroll
            for (int r = 0; r < 4; r++) {
                const float v0 = acc[f][0][r], v1 = acc[f][1][r];
                s0 += v0; q0 = fmaf(v0, v0, q0);
                s1 += v1; q1 = fmaf(v1, v1, q1);
            }
        // sum the 4 kq row-groups (lanes mrow, +16, +32, +48)
#pragma unroll
        for (int m = 16; m < 64; m <<= 1) {
            s0 += __shfl_xor(s0, m, 64);
            q0 += __shfl_xor(q0, m, 64);
            s1 += __shfl_xor(s1, m, 64);
            q1 += __shfl_xor(q1, m, 64);
        }
        if (lane < 16) {
            red[w][mrow]      = s0;
            red[w][16 + mrow] = s1;
            red[w][32 + mrow] = q0;
            red[w][48 + mrow] = q1;
        }
    }
    __syncthreads();
    if (tid < 64)
        part[(((size_t)p * NTILE) + blockIdx.x) * 64 + tid] =
            red[0][tid] + red[1][tid] + red[2][tid] + red[3][tid];

    // writeback from regs: row = j0 + w*64 + 16f + kq*4 + r, cols mrow/16+mrow
#pragma unroll
    for (int f = 0; f < 4; f++)
#pragma unroll
        for (int r = 0; r < 4; r++) {
            const int row = j0 + w * 64 + 16 * f + kq * 4 + r;
            float* dst = Cb + (size_t)row * CIN + p * CPATH;
            dst[mrow]      = acc[f][0][r];
            dst[16 + mrow] = acc[f][1][r];
        }
}

// ---------------------------------------------------------------------------
// BN finalize: reduce per-tile partials -> scale/shift per channel.
// ---------------------------------------------------------------------------
__global__ void bn_stats2(const float* __restrict__ part,
                          const float* __restrict__ gamma,
                          const float* __restrict__ beta,
                          float* __restrict__ ss) {
    const int c = threadIdx.x;  // 0..127
    const int p = c >> 5, cc = c & 31;
    float s = 0.f, s2 = 0.f;
    for (int t = 0; t < NTILE; t++) {
        s += part[(((size_t)p * NTILE) + t) * 64 + cc];
        s2 += part[(((size_t)p * NTILE) + t) * 64 + 32 + cc];
    }
    const float mean = s * (1.f / NN);
    const float var = s2 * (1.f / NN) - mean * mean;
    const float sc = gamma[c] * rsqrtf(var + 1e-5f);
    ss[c] = sc;
    ss[128 + c] = beta[c] - mean * sc;
}

// ---------------------------------------------------------------------------
// Final GEMM: out = relu(norm(Cb)) @ finW + finb + feats
// ---------------------------------------------------------------------------
__global__ void fin_gemm(const float* __restrict__ Cb,
                         const float* __restrict__ scale,
                         const float* __restrict__ shift,
                         const float* __restrict__ finW,
                         const float* __restrict__ finb,
                         const float* __restrict__ feats,
                         float* __restrict__ out) {
    __shared__ float As[32][132];
    __shared__ float Bs[32][132];
    const int tid = threadIdx.x;
    const int row0 = blockIdx.x * 128;
    const int rg = tid >> 4, cg = tid & 15;

    float acc[8][8];
#pragma unroll
    for (int i = 0; i < 8; i++)
#pragma unroll
        for (int j = 0; j < 8; j++) acc[i][j] = 0.f;

    for (int kt = 0; kt < 4; ++kt) {
        {
            const int r = tid >> 3;
            const int kq = tid & 7;
            const int kbase = kt * 32 + kq * 4;
            const float sc0 = scale[kbase + 0], sh0 = shift[kbase + 0];
            const float sc1 = scale[kbase + 1], sh1 = shift[kbase + 1];
            const float sc2 = scale[kbase + 2], sh2 = shift[kbase + 2];
            const float sc3 = scale[kbase + 3], sh3 = shift[kbase + 3];
#pragma unroll
            for (int i = 0; i < 4; i++) {
                const float4 v = *(const float4*)(Cb +
                    (size_t)(row0 + r + 32 * i) * CIN + kbase);
                As[kq * 4 + 0][r + 32 * i] = fmaxf(fmaf(v.x, sc0, sh0), 0.f);
                As[kq * 4 + 1][r + 32 * i] = fmaxf(fmaf(v.y, sc1, sh1), 0.f);
                As[kq * 4 + 2][r + 32 * i] = fmaxf(fmaf(v.z, sc2, sh2), 0.f);
                As[kq * 4 + 3][r + 32 * i] = fmaxf(fmaf(v.w, sc3, sh3), 0.f);
            }
        }
        {
            const int col4 = (tid & 31) * 4;
            const int kk0 = tid >> 5;
#pragma unroll
            for (int i = 0; i < 4; i++) {
                const int kk = kk0 + 8 * i;
                const float4 w = *(const float4*)(finW +
                    (size_t)(kt * 32 + kk) * CIN + col4);
                *(float4*)&Bs[kk][col4] = w;
            }
        }
        __syncthreads();
#pragma unroll
        for (int kk = 0; kk < 32; kk++) {
            float a[8], b[8];
            *(float4*)&a[0] = *(const float4*)&As[kk][rg * 8];
            *(float4*)&a[4] = *(const float4*)&As[kk][rg * 8 + 4];
            *(float4*)&b[0] = *(const float4*)&Bs[kk][cg * 8];
            *(float4*)&b[4] = *(const float4*)&Bs[kk][cg * 8 + 4];
#pragma unroll
            for (int i = 0; i < 8; i++)
#pragma unroll
                for (int j = 0; j < 8; j++)
                    acc[i][j] = fmaf(a[i], b[j], acc[i][j]);
        }
        __syncthreads();
    }
    float fb[8];
#pragma unroll
    for (int j = 0; j < 8; j++) fb[j] = finb[cg * 8 + j];
#pragma unroll
    for (int i = 0; i < 8; i++) {
        const int row = row0 + rg * 8 + i;
        const float4 r0 = *(const float4*)(feats + (size_t)row * CIN + cg * 8);
        const float4 r1 = *(const float4*)(feats + (size_t)row * CIN + cg * 8 + 4);
        float4 o0, o1;
        o0.x = acc[i][0] + fb[0] + r0.x; o0.y = acc[i][1] + fb[1] + r0.y;
        o0.z = acc[i][2] + fb[2] + r0.z; o0.w = acc[i][3] + fb[3] + r0.w;
        o1.x = acc[i][4] + fb[4] + r1.x; o1.y = acc[i][5] + fb[5] + r1.y;
        o1.z = acc[i][6] + fb[6] + r1.z; o1.w = acc[i][7] + fb[7] + r1.w;
        *(float4*)(out + (size_t)row * CIN + cg * 8) = o0;
        *(float4*)(out + (size_t)row * CIN + cg * 8 + 4) = o1;
    }
}

// ---------------------------------------------------------------------------
extern "C" void kernel_launch(void* const* d_in, const int* in_sizes, int n_in,
                              void* d_out, int out_size, void* d_ws,
                              size_t ws_size, hipStream_t stream) {
    (void)in_sizes; (void)n_in; (void)out_size; (void)ws_size;
    const float* feats = (const float*)d_in[0];
    const float* linW  = (const float*)d_in[1];
    const float* linb  = (const float*)d_in[2];
    const float* convW = (const float*)d_in[3];
    const float* gamma = (const float*)d_in[4];
    const float* beta  = (const float*)d_in[5];
    const float* finW  = (const float*)d_in[6];
    const float* finb  = (const float*)d_in[7];
    const int*   im    = (const int*)d_in[8];
    const int*   om    = (const int*)d_in[9];
    float* out = (float*)d_out;

    char* ws = (char*)d_ws;
    unsigned short* Hb = (unsigned short*)(ws);            // (NN+1)*128*2 = 16,777,472 B
    float* Cb          = (float*)(ws + 16781312);          // 33,554,432 B
    unsigned short* Wt = (unsigned short*)(ws + 50335744); //    221,184 B
    float* part        = (float*)(ws + 50556928);          //    262,144 B
    float* ss          = (float*)(ws + 50819072);          //      1,024 B

    wprep<<<NPATH * NK, 256, 0, stream>>>(convW, Wt, Hb);
    lin_gemm<<<512, 256, 0, stream>>>(feats, linW, linb, Hb);
    sconv4<<<dim3(NTILE, NPATH), 256, 0, stream>>>(Hb, Wt, im, om, Cb, part);
    bn_stats2<<<1, 128, 0, stream>>>(part, gamma, beta, ss);
    fin_gemm<<<512, 256, 0, stream>>>(Cb, ss, ss + 128, finW, finb, feats, out);
}